// Round 7
// baseline (576.717 us; speedup 1.0000x reference)
//
#include <hip/hip_runtime.h>

// SVDQuantLinear: out[m,n] = x[m,:] . (w_q[n,:]*w_scale[n]) + bias[n] + lora
// Fold rank-32 LoRA into dequantized W (fp32, one bf16 round) -> one bf16 GEMM.
// R3: 256x256/BK=32 ring-4 -> 258-273us, MfmaUtil 46-48%. R4/R5/R6 FAILED.
// R7: anchor 533us = ~220 fixed + ~40 prep + ~273 gemm.
// R8: reg double-buffer -> 261us (+4%), MfmaUtil still 46%. Corrected cycle
//     model: MFMA floor is 1242 cy/CU/tile (ubench is CU-aggregate), measured
//     2447 -> per-GATE overhead ~1200 cy is the bottleneck, not LDS/L2 BW.
// R9 (this round): HALVE THE GATE COUNT. BK=64, ring-2 (same 128 KiB LDS),
//     R3-exact per-tile schedule {stage t+1 | 24 ds_read | lgkm drain |
//     setprio 64-MFMA cluster | vmcnt(0)+barrier}. MFMA burst/gate 2x
//     (2484 cy) against ~constant gate overhead -> predicted util ~60-68%.
//     New 128B-row swizzle: bank = 16B-slot only, so full 3-bit XOR
//     slot ^= row&7 (via pre-swizzled GLOBAL source, rule #21) gives the
//     uniform 8-lanes-per-bank-quad spread = b128 minimum (counted 0).

#define M_DIM 8192   // B*S
#define N_DIM 4096   // D_OUT
#define K_DIM 4096   // D_IN
#define R_DIM 32

#define BM 256
#define BN 256
#define BK 64                 // 128 B per row in LDS
#define NT2 (K_DIM / BK)      // 64 k-tiles
#define NSLOT 2               // ring-2: 2 * (32KB A + 32KB B) = 128 KiB

typedef short bf16x8 __attribute__((ext_vector_type(8)));
typedef float f32x4 __attribute__((ext_vector_type(4)));
typedef unsigned short u16x8 __attribute__((ext_vector_type(8)));

#define GLOBAL_AS __attribute__((address_space(1)))
#define LDS_AS __attribute__((address_space(3)))

__device__ __forceinline__ unsigned short f2bf(float f) {
  union { float f; unsigned u; } v;
  v.f = f;
  unsigned u = v.u;
  u += 0x7fffu + ((u >> 16) & 1u);  // RNE (finite inputs)
  return (unsigned short)(u >> 16);
}

// ---------------- fused prep: cast x -> bf16 AND fold W_eff -> bf16 --------
#define CAST_BLOCKS 16384
__global__ void prep_kernel(const float* __restrict__ x,
                            const int* __restrict__ wq,
                            const float* __restrict__ wscale,
                            const float* __restrict__ lA,
                            const float* __restrict__ lS,
                            const float* __restrict__ lB,
                            unsigned short* __restrict__ Xbf,
                            unsigned short* __restrict__ Wbf) {
  __shared__ float bs[4][32];
  const int tid = threadIdx.x;

  if (blockIdx.x < CAST_BLOCKS) {
    size_t i = ((size_t)blockIdx.x * 256 + tid) * 8;
    float4 v0 = *(const float4*)(x + i);
    float4 v1 = *(const float4*)(x + i + 4);
    u16x8 o;
    o[0] = f2bf(v0.x); o[1] = f2bf(v0.y); o[2] = f2bf(v0.z); o[3] = f2bf(v0.w);
    o[4] = f2bf(v1.x); o[5] = f2bf(v1.y); o[6] = f2bf(v1.z); o[7] = f2bf(v1.w);
    *(u16x8*)(Xbf + i) = o;
    return;
  }

  const int bid2 = (int)blockIdx.x - CAST_BLOCKS;   // 0..2047
  const int o0 = (bid2 >> 1) * 4;                   // 1024 o-blocks x 4 rows
  const int i0 = (bid2 & 1) * 2048 + tid * 8;       // 2 i-blocks

  if (tid < 128) {
    int o = tid >> 5, r = tid & 31;
    bs[o][r] = lB[(size_t)(o0 + o) * R_DIM + r] * lS[r];
  }
  __syncthreads();

  float acc[4][8];
#pragma unroll
  for (int o = 0; o < 4; ++o)
#pragma unroll
    for (int j = 0; j < 8; ++j) acc[o][j] = 0.f;

  for (int r = 0; r < R_DIM; ++r) {
    float4 a0 = *(const float4*)(lA + (size_t)r * K_DIM + i0);
    float4 a1 = *(const float4*)(lA + (size_t)r * K_DIM + i0 + 4);
    float av[8] = {a0.x, a0.y, a0.z, a0.w, a1.x, a1.y, a1.z, a1.w};
#pragma unroll
    for (int o = 0; o < 4; ++o) {
      float b = bs[o][r];
#pragma unroll
      for (int j = 0; j < 8; ++j) acc[o][j] += b * av[j];
    }
  }

#pragma unroll
  for (int o = 0; o < 4; ++o) {
    float sc = wscale[o0 + o];
    const int* qp = wq + (size_t)(o0 + o) * K_DIM + i0;
    int4 q0 = *(const int4*)qp;
    int4 q1 = *(const int4*)(qp + 4);
    int qv[8] = {q0.x, q0.y, q0.z, q0.w, q1.x, q1.y, q1.z, q1.w};
    u16x8 ov;
#pragma unroll
    for (int j = 0; j < 8; ++j) ov[j] = f2bf(acc[o][j] + (float)qv[j] * sc);
    *(u16x8*)(Wbf + (size_t)(o0 + o) * K_DIM + i0) = ov;
  }
}

// ---------------- main GEMM: C = Xbf * Wbf^T + bias ------------------------
// 256x256 tile, BK=64, 512 thr = 8 waves (2M x 4N), wave = 128x64 output.
// Per tile: 64 MFMA/wave (8mf x 4nf x 2ks of 16x16x32), 24 ds_read_b128.
// Ring-2 LDS (2 x 32KB per operand). One gate per tile.
// LDS layout: [256 rows][64 k] bf16, 128 B/row = 8 x 16B slots; slot s of
// row r holds global k-chunk s ^ (r&7). Staging: lane l -> row l>>3,
// linear LDS slot l&7, pre-swizzled global chunk (l&7)^(l>>3) (rule #21).
__global__ __launch_bounds__(512, 2) void gemm_bias_kernel(
    const unsigned short* __restrict__ A,   // [M, K] bf16 bits
    const unsigned short* __restrict__ B,   // [N, K] bf16 bits
    const float* __restrict__ bias,         // [N]
    float* __restrict__ C) {                // [M, N]
  __shared__ __align__(16) unsigned short sA[NSLOT][BM * BK];  // 2 x 32 KiB
  __shared__ __align__(16) unsigned short sB[NSLOT][BN * BK];  // 2 x 32 KiB

  const int tid = threadIdx.x;
  const int lane = tid & 63;
  const int wv = tid >> 6;      // 0..7
  const int wm = wv >> 2;       // 0..1
  const int wn = wv & 3;        // 0..3

  // T1: bijective XCD swizzle (grid = 512 = 8*64). XCD x owns 2 B-panels.
  const int bid = (int)blockIdx.x;
  const int s = ((bid & 7) << 6) + (bid >> 3);
  const int bn_ = s >> 5;       // 0..15
  const int bm_ = s & 31;       // 0..31
  const size_t m0 = (size_t)bm_ * BM;
  const size_t n0 = (size_t)bn_ * BN;

  // ---- staging: per instruction (8 rows x 128B = 1KB): lane l -> local row
  // l>>3, LDS 16B slot l&7 (linear dest), global k-chunk (l&7)^(l>>3).
  // Wave wv covers rows [wv*32, wv*32+32) in 4 instructions per operand.
  const int lrow8 = lane >> 3;                                 // 0..7
  const int gsl = ((lane & 7) ^ lrow8) * 8;                    // k elems
  const int rA = wv * 32 + lrow8;
  const unsigned short* gA = A + (m0 + rA) * (size_t)K_DIM + gsl;
  const unsigned short* gB = B + (n0 + rA) * (size_t)K_DIM + gsl;
  const int chb = wv * 2048;    // LDS chunk base (shorts): wv*32 rows * 64

#define STAGE_ALL(kt, sl_)                                                    \
  do {                                                                        \
    const size_t ko = (size_t)(kt)*BK;                                        \
    _Pragma("unroll")                                                         \
    for (int c = 0; c < 4; ++c) {                                             \
      __builtin_amdgcn_global_load_lds(                                       \
          (const GLOBAL_AS void*)(gA + ko + (size_t)c * 8 * K_DIM),           \
          (LDS_AS void*)(&sA[sl_][chb + c * 512]), 16, 0, 0);                 \
      __builtin_amdgcn_global_load_lds(                                       \
          (const GLOBAL_AS void*)(gB + ko + (size_t)c * 8 * K_DIM),           \
          (LDS_AS void*)(&sB[sl_][chb + c * 512]), 16, 0, 0);                 \
    }                                                                         \
  } while (0)

  // ---- read addressing (16x16x32 frag: m = lane&15, k = kgrp*8+j;
  // tile k = ks*32 + kgrp*8 + j -> chunk ks*4+kgrp, swizzled by row&7)
  const int rdrow = lane & 15;
  const int kgrp = lane >> 4;
  const int s0 = (kgrp ^ (rdrow & 7)) * 8;          // ks=0 slot (shorts)
  const int s1 = ((4 + kgrp) ^ (rdrow & 7)) * 8;    // ks=1 slot
  const int ar = (wm * 128 + rdrow) * 64;           // + mf*1024
  const int br = (wn * 64 + rdrow) * 64;            // + nf*1024

  f32x4 acc[8][4];
#pragma unroll
  for (int mf = 0; mf < 8; ++mf)
#pragma unroll
    for (int nf = 0; nf < 4; ++nf) acc[mf][nf] = (f32x4){0.f, 0.f, 0.f, 0.f};

  // ---- prologue: stage tile 0, drain, barrier.
  STAGE_ALL(0, 0);
  asm volatile("s_waitcnt vmcnt(0)" ::: "memory");
  __builtin_amdgcn_s_barrier();
  asm volatile("" ::: "memory");

  for (int t = 0; t < NT2; ++t) {
    const int sl = t & 1;
    // stage next tile first (earliest issue; writes the slot last read at
    // tile t-1, one barrier ago -> safe).
    if (t + 1 < NT2) STAGE_ALL(t + 1, (t + 1) & 1);

    bf16x8 af[2][8], bfr[2][4];
#pragma unroll
    for (int nf = 0; nf < 4; ++nf) {
      bfr[0][nf] = *(const bf16x8*)&sB[sl][br + nf * 1024 + s0];
      bfr[1][nf] = *(const bf16x8*)&sB[sl][br + nf * 1024 + s1];
    }
#pragma unroll
    for (int mf = 0; mf < 8; ++mf) {
      af[0][mf] = *(const bf16x8*)&sA[sl][ar + mf * 1024 + s0];
      af[1][mf] = *(const bf16x8*)&sA[sl][ar + mf * 1024 + s1];
    }

    // drain frag reads, pin, tight 64-MFMA cluster (R3-proven pattern).
    asm volatile("s_waitcnt lgkmcnt(0)" ::: "memory");
    __builtin_amdgcn_sched_barrier(0);
    __builtin_amdgcn_s_setprio(1);
#pragma unroll
    for (int ks = 0; ks < 2; ++ks)
#pragma unroll
      for (int mf = 0; mf < 8; ++mf)
#pragma unroll
        for (int nf = 0; nf < 4; ++nf)
          acc[mf][nf] = __builtin_amdgcn_mfma_f32_16x16x32_bf16(
              af[ks][mf], bfr[ks][nf], acc[mf][nf], 0, 0, 0);
    __builtin_amdgcn_s_setprio(0);

    // gate: tile t+1's 8 loads were issued ~>=1400 cy ago (reads + MFMA
    // cluster) >= HBM latency -> vmcnt(0) is ~free. One barrier per tile.
    if (t < NT2 - 1) {
      asm volatile("s_waitcnt vmcnt(0)" ::: "memory");
      __builtin_amdgcn_s_barrier();
      asm volatile("" ::: "memory");
    }
  }
#undef STAGE_ALL

  // ---- epilogue: 16x16 C/D layout col = lane&15, row = (lane>>4)*4 + r
#pragma unroll
  for (int nf = 0; nf < 4; ++nf) {
    const int n = (int)n0 + wn * 64 + nf * 16 + (lane & 15);
    const float bv = bias[n];
#pragma unroll
    for (int mf = 0; mf < 8; ++mf) {
      const size_t mb = m0 + wm * 128 + mf * 16 + (lane >> 4) * 4;
#pragma unroll
      for (int r = 0; r < 4; ++r) {
        C[(mb + r) * N_DIM + n] = acc[mf][nf][r] + bv;
      }
    }
  }
}

// ---------------- fallback (only if ws too small) -------------------------
__global__ void fallback_kernel(const float* __restrict__ x,
                                const int* __restrict__ wq,
                                const float* __restrict__ wscale,
                                const float* __restrict__ bias,
                                float* __restrict__ out) {
  __shared__ float xs[K_DIM];
  const size_t m = blockIdx.x;
  for (int k = threadIdx.x; k < K_DIM; k += 256) xs[k] = x[m * K_DIM + k];
  __syncthreads();
  for (int n = threadIdx.x; n < N_DIM; n += 256) {
    const int* wr = wq + (size_t)n * K_DIM;
    float s = 0.f;
    for (int k = 0; k < K_DIM; ++k) s += xs[k] * (float)wr[k];
    out[m * N_DIM + n] = s * wscale[n] + bias[n];
  }
}

extern "C" void kernel_launch(void* const* d_in, const int* in_sizes, int n_in,
                              void* d_out, int out_size, void* d_ws, size_t ws_size,
                              hipStream_t stream) {
  const float* x       = (const float*)d_in[0];
  const int*   w_q     = (const int*)d_in[1];
  const float* w_scale = (const float*)d_in[2];
  const float* bias    = (const float*)d_in[3];
  const float* lora_A  = (const float*)d_in[4];
  const float* lora_S  = (const float*)d_in[5];
  const float* lora_B  = (const float*)d_in[6];
  float* out = (float*)d_out;

  const size_t need = ((size_t)M_DIM + N_DIM) * K_DIM * sizeof(unsigned short); // 96 MB
  if (ws_size < need) {
    fallback_kernel<<<M_DIM, 256, 0, stream>>>(x, w_q, w_scale, bias, out);
    return;
  }

  unsigned short* Xbf = (unsigned short*)d_ws;
  unsigned short* Wbf = Xbf + (size_t)M_DIM * K_DIM;

  prep_kernel<<<CAST_BLOCKS + (N_DIM / 4) * (K_DIM / 2048), 256, 0, stream>>>(
      x, w_q, w_scale, lora_A, lora_S, lora_B, Xbf, Wbf);
  gemm_bias_kernel<<<dim3((N_DIM / BN) * (M_DIM / BM)), 512, 0, stream>>>(
      Xbf, Wbf, bias, out);
}

// Round 8
// 571.367 us; speedup vs baseline: 1.0094x; 1.0094x over previous
//
#include <hip/hip_runtime.h>

// SVDQuantLinear: out[m,n] = x[m,:] . (w_q[n,:]*w_scale[n]) + bias[n] + lora
// Fold rank-32 LoRA into dequantized W (fp32, one bf16 round) -> one bf16 GEMM.
// R3: 256x256/BK=32 ring-4 counted-vmcnt -> 258-273us, MfmaUtil 46-48%.
// R4 FAILED coarse 2-phase (298us). R5 FAILED drain-removal (268us).
// R6 FAILED fp32-A reg-staging (366us). R8: reg-dbuf 261us (+4%).
// R9 FAILED BK=64 ring-2 (310us): vmcnt(0) drain/gate costs ~2200cy. LESSON:
//     counted-vmcnt mandatory; coarse structure capped at 46-48%.
// R10 (this round): faithful 8-phase fine-interleave port (m201 regime,
//     identical geometry: 256sq, 8 waves 2Mx4N, BK=64, 128KiB, 16x16x32).
//     Per K-step 4 phases {reads | stage 1 half-tile | barrier | lgkm(0) |
//     setprio 16-MFMA | barrier}; stage schedule p0:B(s+1)h0 p1:B(s+1)h1
//     p2:A(s+2)h0 p3:A(s+2)h1; counted vmcnt(4) once per step at p3 (never
//     drains). Region-free proof: readers retire at prev phase's lgkm(0),
//     >=1 barrier before stage issue; tiles land >=4 phases before read.
//     Read/stage swizzle identical to R9's refcheck-passed BK=64 layout.

#define M_DIM 8192   // B*S
#define N_DIM 4096   // D_OUT
#define K_DIM 4096   // D_IN
#define R_DIM 32

#define BM 256
#define BN 256
#define BK 64                 // K-step; 128 B per LDS row
#define NKS (K_DIM / BK)      // 64 K-steps

typedef short bf16x8 __attribute__((ext_vector_type(8)));
typedef float f32x4 __attribute__((ext_vector_type(4)));
typedef unsigned short u16x8 __attribute__((ext_vector_type(8)));

#define GLOBAL_AS __attribute__((address_space(1)))
#define LDS_AS __attribute__((address_space(3)))

__device__ __forceinline__ unsigned short f2bf(float f) {
  union { float f; unsigned u; } v;
  v.f = f;
  unsigned u = v.u;
  u += 0x7fffu + ((u >> 16) & 1u);  // RNE (finite inputs)
  return (unsigned short)(u >> 16);
}

// ---------------- fused prep: cast x -> bf16 AND fold W_eff -> bf16 --------
#define CAST_BLOCKS 16384
__global__ void prep_kernel(const float* __restrict__ x,
                            const int* __restrict__ wq,
                            const float* __restrict__ wscale,
                            const float* __restrict__ lA,
                            const float* __restrict__ lS,
                            const float* __restrict__ lB,
                            unsigned short* __restrict__ Xbf,
                            unsigned short* __restrict__ Wbf) {
  __shared__ float bs[4][32];
  const int tid = threadIdx.x;

  if (blockIdx.x < CAST_BLOCKS) {
    size_t i = ((size_t)blockIdx.x * 256 + tid) * 8;
    float4 v0 = *(const float4*)(x + i);
    float4 v1 = *(const float4*)(x + i + 4);
    u16x8 o;
    o[0] = f2bf(v0.x); o[1] = f2bf(v0.y); o[2] = f2bf(v0.z); o[3] = f2bf(v0.w);
    o[4] = f2bf(v1.x); o[5] = f2bf(v1.y); o[6] = f2bf(v1.z); o[7] = f2bf(v1.w);
    *(u16x8*)(Xbf + i) = o;
    return;
  }

  const int bid2 = (int)blockIdx.x - CAST_BLOCKS;   // 0..2047
  const int o0 = (bid2 >> 1) * 4;                   // 1024 o-blocks x 4 rows
  const int i0 = (bid2 & 1) * 2048 + tid * 8;       // 2 i-blocks

  if (tid < 128) {
    int o = tid >> 5, r = tid & 31;
    bs[o][r] = lB[(size_t)(o0 + o) * R_DIM + r] * lS[r];
  }
  __syncthreads();

  float acc[4][8];
#pragma unroll
  for (int o = 0; o < 4; ++o)
#pragma unroll
    for (int j = 0; j < 8; ++j) acc[o][j] = 0.f;

  for (int r = 0; r < R_DIM; ++r) {
    float4 a0 = *(const float4*)(lA + (size_t)r * K_DIM + i0);
    float4 a1 = *(const float4*)(lA + (size_t)r * K_DIM + i0 + 4);
    float av[8] = {a0.x, a0.y, a0.z, a0.w, a1.x, a1.y, a1.z, a1.w};
#pragma unroll
    for (int o = 0; o < 4; ++o) {
      float b = bs[o][r];
#pragma unroll
      for (int j = 0; j < 8; ++j) acc[o][j] += b * av[j];
    }
  }

#pragma unroll
  for (int o = 0; o < 4; ++o) {
    float sc = wscale[o0 + o];
    const int* qp = wq + (size_t)(o0 + o) * K_DIM + i0;
    int4 q0 = *(const int4*)qp;
    int4 q1 = *(const int4*)(qp + 4);
    int qv[8] = {q0.x, q0.y, q0.z, q0.w, q1.x, q1.y, q1.z, q1.w};
    u16x8 ov;
#pragma unroll
    for (int j = 0; j < 8; ++j) ov[j] = f2bf(acc[o][j] + (float)qv[j] * sc);
    *(u16x8*)(Wbf + (size_t)(o0 + o) * K_DIM + i0) = ov;
  }
}

// ---------------- main GEMM: C = Xbf * Wbf^T + bias ------------------------
// 256x256 tile, BK=64, 512 thr = 8 waves (2M x 4N), wave = 128x64 output =
// 8x4 frags x 2 k-halves of 16x16x32 MFMA. Double-buffered LDS (b = s&1),
// 4 fine phases per K-step, counted vmcnt(4) gate once per step.
// LDS: [256 rows][64 k] bf16, 8 x 16B slots/row; slot sl of row r holds
// global k-chunk sl ^ (r&7). Staging: lane l -> row l>>3, linear slot l&7,
// pre-swizzled global chunk (l&7)^(l>>3) (rule #21; R9-refcheck-passed).
__global__ __launch_bounds__(512, 2) void gemm_bias_kernel(
    const unsigned short* __restrict__ A,   // [M, K] bf16 bits
    const unsigned short* __restrict__ B,   // [N, K] bf16 bits
    const float* __restrict__ bias,         // [N]
    float* __restrict__ C) {                // [M, N]
  __shared__ __align__(16) unsigned short sA[2][BM * BK];  // 2 x 32 KiB
  __shared__ __align__(16) unsigned short sB[2][BN * BK];  // 2 x 32 KiB

  const int tid = threadIdx.x;
  const int lane = tid & 63;
  const int wv = tid >> 6;      // 0..7
  const int wm = wv >> 2;       // 0..1
  const int wn = wv & 3;        // 0..3

  // T1: bijective XCD swizzle (grid = 512 = 8*64). XCD x owns 2 B-panels.
  const int bid = (int)blockIdx.x;
  const int sw = ((bid & 7) << 6) + (bid >> 3);
  const int bn_ = sw >> 5;      // 0..15
  const int bm_ = sw & 31;      // 0..31
  const size_t m0 = (size_t)bm_ * BM;
  const size_t n0 = (size_t)bn_ * BN;

  // ---- staging: per gload_lds: 8 rows x 128B; lane l -> row l>>3, LDS slot
  // l&7 (linear dest), global k-chunk (l&7)^(l>>3). Wave wv owns rows
  // h*128 + wv*16 + c*8 + (l>>3) for c in {0,1}: 2 instrs per half-tile.
  const int lrow8 = lane >> 3;                                 // 0..7
  const int gsl = ((lane & 7) ^ lrow8) * 8;                    // k elems
  const unsigned short* gA_st = A + (m0 + wv * 16 + lrow8) * (size_t)K_DIM + gsl;
  const unsigned short* gB_st = B + (n0 + wv * 16 + lrow8) * (size_t)K_DIM + gsl;

#define STAGE_A(buf_, h_, st_)                                                \
  do {                                                                        \
    const size_t ko_ = (size_t)(st_)*BK;                                      \
    _Pragma("unroll")                                                         \
    for (int c = 0; c < 2; ++c)                                               \
      __builtin_amdgcn_global_load_lds(                                       \
          (const GLOBAL_AS void*)(gA_st + ko_ +                               \
                                  (size_t)((h_)*128 + c * 8) * K_DIM),        \
          (LDS_AS void*)(&sA[buf_][((h_)*128 + wv * 16 + c * 8) * 64]),       \
          16, 0, 0);                                                          \
  } while (0)
#define STAGE_B(buf_, h_, st_)                                                \
  do {                                                                        \
    const size_t ko_ = (size_t)(st_)*BK;                                      \
    _Pragma("unroll")                                                         \
    for (int c = 0; c < 2; ++c)                                               \
      __builtin_amdgcn_global_load_lds(                                       \
          (const GLOBAL_AS void*)(gB_st + ko_ +                               \
                                  (size_t)((h_)*128 + c * 8) * K_DIM),        \
          (LDS_AS void*)(&sB[buf_][((h_)*128 + wv * 16 + c * 8) * 64]),       \
          16, 0, 0);                                                          \
  } while (0)

  // ---- read addressing (16x16x32 frag: m = lane&15, k = kgrp*8+j;
  // k-half ks -> chunk ks*4+kgrp -> slot (chunk)^(row&7); row&7 == rdrow&7)
  const int rdrow = lane & 15;
  const int kgrp = lane >> 4;
  const int s0 = (kgrp ^ (rdrow & 7)) * 8;          // ks=0 slot (shorts)
  const int s1 = ((4 + kgrp) ^ (rdrow & 7)) * 8;    // ks=1 slot
  const int ar = (wm * 128 + rdrow) * 64;           // + mf*1024
  const int br = (wn * 64 + rdrow) * 64;            // + nf*1024

  // phase boilerplate: [reads|stage already issued] barrier; lgkm drain;
  // pin; hot MFMA; then phase-end barrier.
#define PH_PRE                                                                \
  do {                                                                        \
    asm volatile("" ::: "memory");                                            \
    __builtin_amdgcn_s_barrier();                                             \
    asm volatile("s_waitcnt lgkmcnt(0)" ::: "memory");                        \
    __builtin_amdgcn_sched_barrier(0);                                        \
    __builtin_amdgcn_s_setprio(1);                                            \
  } while (0)
#define PH_POST                                                               \
  do {                                                                        \
    __builtin_amdgcn_s_setprio(0);                                            \
    asm volatile("" ::: "memory");                                            \
    __builtin_amdgcn_s_barrier();                                             \
    asm volatile("" ::: "memory");                                            \
  } while (0)
#define MFMA16(AARR, BARR, MF0)                                               \
  _Pragma("unroll")                                                           \
  for (int mf = 0; mf < 4; ++mf)                                              \
    _Pragma("unroll")                                                         \
    for (int nf = 0; nf < 4; ++nf)                                            \
      acc[(MF0) + mf][nf] = __builtin_amdgcn_mfma_f32_16x16x32_bf16(          \
          AARR[(MF0) + mf], BARR[nf], acc[(MF0) + mf][nf], 0, 0, 0);

  f32x4 acc[8][4];
#pragma unroll
  for (int mf = 0; mf < 8; ++mf)
#pragma unroll
    for (int nf = 0; nf < 4; ++nf) acc[mf][nf] = (f32x4){0.f, 0.f, 0.f, 0.f};

  // ---- prologue: stage A(0),B(0) -> buf0; A(1) -> buf1. vmcnt(4): A(0),B(0)
  // landed, A(1)'s 4 loads may stay in flight.
  STAGE_A(0, 0, 0); STAGE_A(0, 1, 0);
  STAGE_B(0, 0, 0); STAGE_B(0, 1, 0);
  STAGE_A(1, 0, 1); STAGE_A(1, 1, 1);
  asm volatile("s_waitcnt vmcnt(4)" ::: "memory");
  __builtin_amdgcn_s_barrier();
  asm volatile("" ::: "memory");

  for (int s = 0; s < NKS; ++s) {
    const int b = s & 1;
    bf16x8 a0[8], a1[8], b0[4], b1[4];

    // ---- p0: reads A-ks0(8)+B-ks0(4); stage B(s+1)h0; MFMA mf0-3 ks0
#pragma unroll
    for (int nf = 0; nf < 4; ++nf)
      b0[nf] = *(const bf16x8*)&sB[b][br + nf * 1024 + s0];
#pragma unroll
    for (int mf = 0; mf < 8; ++mf)
      a0[mf] = *(const bf16x8*)&sA[b][ar + mf * 1024 + s0];
    if (s + 1 < NKS) STAGE_B(b ^ 1, 0, s + 1);
    PH_PRE;
    MFMA16(a0, b0, 0);
    PH_POST;

    // ---- p1: reads A-ks1(8); stage B(s+1)h1; MFMA mf4-7 ks0
#pragma unroll
    for (int mf = 0; mf < 8; ++mf)
      a1[mf] = *(const bf16x8*)&sA[b][ar + mf * 1024 + s1];
    if (s + 1 < NKS) STAGE_B(b ^ 1, 1, s + 1);
    PH_PRE;
    MFMA16(a0, b0, 4);
    PH_POST;

    // ---- p2: reads B-ks1(4); stage A(s+2)h0; MFMA mf0-3 ks1
#pragma unroll
    for (int nf = 0; nf < 4; ++nf)
      b1[nf] = *(const bf16x8*)&sB[b][br + nf * 1024 + s1];
    if (s + 2 < NKS) STAGE_A(b, 0, s + 2);
    PH_PRE;
    MFMA16(a1, b1, 0);
    PH_POST;

    // ---- p3: stage A(s+2)h1; MFMA mf4-7 ks1; counted gate, step barrier
    if (s + 2 < NKS) STAGE_A(b, 1, s + 2);
    PH_PRE;
    MFMA16(a1, b1, 4);
    __builtin_amdgcn_s_setprio(0);
    if (s + 1 < NKS) {
      // gate: everything except this step's A(s+2) stages (4 loads) must
      // have landed -> B(s+1) + A(s+1) resident for the next step.
      if (s + 2 < NKS) {
        asm volatile("s_waitcnt vmcnt(4)" ::: "memory");
      } else {
        asm volatile("s_waitcnt vmcnt(0)" ::: "memory");
      }
      asm volatile("" ::: "memory");
      __builtin_amdgcn_s_barrier();
      asm volatile("" ::: "memory");
    }
  }
#undef STAGE_A
#undef STAGE_B
#undef PH_PRE
#undef PH_POST
#undef MFMA16

  // ---- epilogue: 16x16 C/D layout col = lane&15, row = (lane>>4)*4 + r
#pragma unroll
  for (int nf = 0; nf < 4; ++nf) {
    const int n = (int)n0 + wn * 64 + nf * 16 + (lane & 15);
    const float bv = bias[n];
#pragma unroll
    for (int mf = 0; mf < 8; ++mf) {
      const size_t mb = m0 + wm * 128 + mf * 16 + (lane >> 4) * 4;
#pragma unroll
      for (int r = 0; r < 4; ++r) {
        C[(mb + r) * N_DIM + n] = acc[mf][nf][r] + bv;
      }
    }
  }
}

// ---------------- fallback (only if ws too small) -------------------------
__global__ void fallback_kernel(const float* __restrict__ x,
                                const int* __restrict__ wq,
                                const float* __restrict__ wscale,
                                const float* __restrict__ bias,
                                float* __restrict__ out) {
  __shared__ float xs[K_DIM];
  const size_t m = blockIdx.x;
  for (int k = threadIdx.x; k < K_DIM; k += 256) xs[k] = x[m * K_DIM + k];
  __syncthreads();
  for (int n = threadIdx.x; n < N_DIM; n += 256) {
    const int* wr = wq + (size_t)n * K_DIM;
    float s = 0.f;
    for (int k = 0; k < K_DIM; ++k) s += xs[k] * (float)wr[k];
    out[m * N_DIM + n] = s * wscale[n] + bias[n];
  }
}

extern "C" void kernel_launch(void* const* d_in, const int* in_sizes, int n_in,
                              void* d_out, int out_size, void* d_ws, size_t ws_size,
                              hipStream_t stream) {
  const float* x       = (const float*)d_in[0];
  const int*   w_q     = (const int*)d_in[1];
  const float* w_scale = (const float*)d_in[2];
  const float* bias    = (const float*)d_in[3];
  const float* lora_A  = (const float*)d_in[4];
  const float* lora_S  = (const float*)d_in[5];
  const float* lora_B  = (const float*)d_in[6];
  float* out = (float*)d_out;

  const size_t need = ((size_t)M_DIM + N_DIM) * K_DIM * sizeof(unsigned short); // 96 MB
  if (ws_size < need) {
    fallback_kernel<<<M_DIM, 256, 0, stream>>>(x, w_q, w_scale, bias, out);
    return;
  }

  unsigned short* Xbf = (unsigned short*)d_ws;
  unsigned short* Wbf = Xbf + (size_t)M_DIM * K_DIM;

  prep_kernel<<<CAST_BLOCKS + (N_DIM / 4) * (K_DIM / 2048), 256, 0, stream>>>(
      x, w_q, w_scale, lora_A, lora_S, lora_B, Xbf, Wbf);
  gemm_bias_kernel<<<dim3((N_DIM / BN) * (M_DIM / BM)), 512, 0, stream>>>(
      Xbf, Wbf, bias, out);
}